// Round 1
// baseline (180.159 us; speedup 1.0000x reference)
//
#include <hip/hip_runtime.h>
#include <hip/hip_bf16.h>
#include <cstdint>
#include <cstddef>

// Problem constants
#define NB 512
#define NM 16
#define ND 128
#define NP 16
#define NT 4096

typedef __bf16 bf16x8 __attribute__((ext_vector_type(8)));
typedef __bf16 bf16x4 __attribute__((ext_vector_type(4)));
typedef float f32x4 __attribute__((ext_vector_type(4)));

static_assert(sizeof(bf16x8) == 16, "bf16x8 must be 16B");

__device__ __forceinline__ void gload_lds16(const void* g, void* l) {
  __builtin_amdgcn_global_load_lds(
      (const __attribute__((address_space(1))) unsigned int*)g,
      (__attribute__((address_space(3))) unsigned int*)l, 16, 0, 0);
}

// ---------------------------------------------------------------------------
// Kernel 1:
//  blocks [0,256):  one m each, 32 b-rows: new_state[b,m,:]=tanh(state@A_m+phi@B_m)
//    A_m (64KB) + B_m (8KB) + state tile (16KB) staged once to LDS via
//    global_load_lds width=16; compute from LDS (ds_read_b128, conflict-free).
//    Outputs: fp32 ns tail, LINEAR bf16 ns image, s_sq.
//  blocks [256,288): t_sq[t] + LINEAR bf16 trajectories.
//  (The old XOR swizzle is gone: kernel 2 no longer uses LDS, so there are no
//   bank conflicts to dodge; linear rows give 64B-coalesced fragment gathers.)
// ---------------------------------------------------------------------------
__global__ __launch_bounds__(256) void prep_kernel(
    const float* __restrict__ phi, const float* __restrict__ state,
    const float* __restrict__ traj, const float* __restrict__ A,
    const float* __restrict__ Bin, float* __restrict__ ns_out,
    __bf16* __restrict__ ns_bf, __bf16* __restrict__ tj_bf,
    float* __restrict__ s_sq, float* __restrict__ t_sq) {
  __shared__ alignas(16) float sA[128 * 128];  // 64 KB: A_m
  __shared__ alignas(16) float sB[16 * 128];   // 8 KB: B_m
  __shared__ alignas(16) float sSt[32 * 128];  // 16 KB: state rows
  __shared__ alignas(16) float sPhi[32 * 16];  // 2 KB: phi rows
  const int tid = threadIdx.x;
  const int bx = blockIdx.x;
  const int lane = tid & 63;
  const int w = tid >> 6;

  if (bx < 256) {
    const int m = bx & 15;
    const int b0 = (bx >> 4) * 32;

    // ---- stage (wave-uniform LDS dest + lane*16 on the global side) ----
    const char* gA = (const char*)(A + (size_t)m * 16384);
    const char* gB = (const char*)(Bin + (size_t)m * 2048);
    const char* gS = (const char*)(state + (size_t)b0 * 128);
#pragma unroll
    for (int it = 0; it < 16; ++it) {  // 64 KB
      const int off = it * 4096 + w * 1024;
      gload_lds16(gA + off + lane * 16, (char*)sA + off);
    }
#pragma unroll
    for (int it = 0; it < 2; ++it) {   // 8 KB
      const int off = it * 4096 + w * 1024;
      gload_lds16(gB + off + lane * 16, (char*)sB + off);
    }
#pragma unroll
    for (int it = 0; it < 4; ++it) {   // 16 KB
      const int off = it * 4096 + w * 1024;
      gload_lds16(gS + off + lane * 16, (char*)sSt + off);
    }
    if (tid < 128)
      ((float4*)sPhi)[tid] = ((const float4*)(phi + (size_t)b0 * 16))[tid];
    __syncthreads();  // drains vmcnt(0) -> staged data visible

    // ---- compute: thread = 4 consecutive cols x 4 rows ----
    const int col4 = (tid & 31) * 4;   // cols col4..col4+3
    const int rgrp = tid >> 5;         // 0..7 -> rows rgrp*4..+3 (local)
    f32x4 acc[4];
#pragma unroll
    for (int j = 0; j < 4; ++j) acc[j] = (f32x4){0.f, 0.f, 0.f, 0.f};

    // state @ A_m   (ascending k, same fma order as before -> identical fp32)
#pragma unroll 4
    for (int kc = 0; kc < 32; ++kc) {
      f32x4 av[4], sv[4];
#pragma unroll
      for (int u = 0; u < 4; ++u)
        av[u] = *(const f32x4*)&sA[(kc * 4 + u) * 128 + col4];
#pragma unroll
      for (int j = 0; j < 4; ++j)
        sv[j] = *(const f32x4*)&sSt[(rgrp * 4 + j) * 128 + kc * 4];
#pragma unroll
      for (int j = 0; j < 4; ++j)
#pragma unroll
        for (int u = 0; u < 4; ++u)
#pragma unroll
          for (int c = 0; c < 4; ++c)
            acc[j][c] = fmaf(sv[j][u], av[u][c], acc[j][c]);
    }
    // phi @ B_m
#pragma unroll
    for (int pc = 0; pc < 4; ++pc) {
      f32x4 bv[4], pv[4];
#pragma unroll
      for (int u = 0; u < 4; ++u)
        bv[u] = *(const f32x4*)&sB[(pc * 4 + u) * 128 + col4];
#pragma unroll
      for (int j = 0; j < 4; ++j)
        pv[j] = *(const f32x4*)&sPhi[(rgrp * 4 + j) * 16 + pc * 4];
#pragma unroll
      for (int j = 0; j < 4; ++j)
#pragma unroll
        for (int u = 0; u < 4; ++u)
#pragma unroll
          for (int c = 0; c < 4; ++c)
            acc[j][c] = fmaf(pv[j][u], bv[u][c], acc[j][c]);
    }

    // ---- epilogue: tanh, fp32 out, linear bf16 out, row norms ----
#pragma unroll
    for (int j = 0; j < 4; ++j) {
      const int row = rgrp * 4 + j;            // local row 0..31
      const int R = (b0 + row) * 16 + m;       // global ns row
      f32x4 v;
      float ss = 0.f;
#pragma unroll
      for (int c = 0; c < 4; ++c) {
        v[c] = tanhf(acc[j][c]);
        ss += v[c] * v[c];
      }
      *(f32x4*)&ns_out[(size_t)R * 128 + col4] = v;
      bf16x4 o;
#pragma unroll
      for (int c = 0; c < 4; ++c) o[c] = (__bf16)v[c];
      *(bf16x4*)(ns_bf + (size_t)R * 128 + col4) = o;
      // reduce across the 32 lanes that share this row (stay inside half-wave)
#pragma unroll
      for (int o2 = 16; o2 > 0; o2 >>= 1) ss += __shfl_xor(ss, o2);
      if ((lane & 31) == 0) s_sq[R] = ss;
    }
  } else {
    // trajectory prep: 128 rows per block, 2 threads per row, linear bf16
    const int t0 = (bx - 256) * 128;
    const int t = t0 + (tid >> 1);
    const int half = tid & 1;
    float s = 0.f;
#pragma unroll
    for (int q = 0; q < 8; ++q) {
      const int kb = half * 8 + q;
      const f32x4 v0 = *(const f32x4*)&traj[(size_t)t * 128 + kb * 8];
      const f32x4 v1 = *(const f32x4*)&traj[(size_t)t * 128 + kb * 8 + 4];
      s += v0[0] * v0[0] + v0[1] * v0[1] + v0[2] * v0[2] + v0[3] * v0[3];
      s += v1[0] * v1[0] + v1[1] * v1[1] + v1[2] * v1[2] + v1[3] * v1[3];
      bf16x8 o;
#pragma unroll
      for (int i = 0; i < 4; ++i) {
        o[i] = (__bf16)v0[i];
        o[i + 4] = (__bf16)v1[i];
      }
      *(bf16x8*)(tj_bf + (size_t)t * 128 + kb * 8) = o;
    }
    s += __shfl_xor(s, 1);  // combine the row's two halves
    if (half == 0) t_sq[t] = s;
  }
}

// ---------------------------------------------------------------------------
// Kernel 2: sim[R,t] = exp(-max(s_sq[R] + t_sq[t] - 2*<ns[R,:],traj[t,:]>, 0))
// 128x128 tile per block. NO LDS, NO barriers: fragments are gathered straight
// from the L2-resident bf16 images (3 MB total). Per load instruction the 4
// quads of a 16-lane group read 4 consecutive 16B chunks of the same row ->
// 16 x 64B coalesced segments. Stores/loads/MFMA pipeline purely through
// occupancy (LDS=0 -> 3+ blocks/CU, no vmcnt(0) drain anywhere).
// ---------------------------------------------------------------------------
__global__ __launch_bounds__(256, 3) void sim_kernel(
    const __bf16* __restrict__ ns_bf, const __bf16* __restrict__ tj_bf,
    const float* __restrict__ s_sq, const float* __restrict__ t_sq,
    float* __restrict__ out) {
  const int tid = threadIdx.x;
  const int lane = tid & 63;
  const int w = tid >> 6;
  const int R0 = blockIdx.x * 128;
  const int C0 = blockIdx.y * 128;
  const int rbase = (w >> 1) * 64;  // ns quadrant
  const int cbase = (w & 1) * 64;   // traj quadrant
  const int l15 = lane & 15;
  const int quad = lane >> 4;

  const __bf16* Ap = ns_bf + (size_t)(R0 + rbase + l15) * 128 + quad * 8;
  const __bf16* Bp = tj_bf + (size_t)(C0 + cbase + l15) * 128 + quad * 8;

  f32x4 acc[4][4];  // [ri = ns subtile][ci = traj subtile]
#pragma unroll
  for (int i = 0; i < 4; ++i)
#pragma unroll
    for (int j = 0; j < 4; ++j) acc[i][j] = (f32x4){0.f, 0.f, 0.f, 0.f};

#pragma unroll
  for (int ks = 0; ks < 4; ++ks) {
    bf16x8 af[4], bfr[4];
#pragma unroll
    for (int i = 0; i < 4; ++i)
      af[i] = *(const bf16x8*)(Ap + i * 2048 + ks * 32);
#pragma unroll
    for (int i = 0; i < 4; ++i)
      bfr[i] = *(const bf16x8*)(Bp + i * 2048 + ks * 32);
#pragma unroll
    for (int ri = 0; ri < 4; ++ri)
#pragma unroll
      for (int ci = 0; ci < 4; ++ci)
        acc[ri][ci] = __builtin_amdgcn_mfma_f32_16x16x32_bf16(
            bfr[ci], af[ri], acc[ri][ci], 0, 0, 0);  // A=traj, B=ns
  }

  // D layout: col(lane&15) = ns row, row(quad*4+reg) = t -> float4 along t
  f32x4 tq[4];
#pragma unroll
  for (int ci = 0; ci < 4; ++ci)
    tq[ci] = *(const f32x4*)&t_sq[C0 + cbase + ci * 16 + quad * 4];
#pragma unroll
  for (int ri = 0; ri < 4; ++ri) {
    const int nsrow = rbase + ri * 16 + l15;
    const float sq = s_sq[R0 + nsrow];
    float* orow = out + (size_t)(R0 + nsrow) * NT + C0;
#pragma unroll
    for (int ci = 0; ci < 4; ++ci) {
      const int t4 = cbase + ci * 16 + quad * 4;
      f32x4 r;
#pragma unroll
      for (int k = 0; k < 4; ++k) {
        const float d = fmaxf(sq + tq[ci][k] - 2.f * acc[ri][ci][k], 0.f);
        r[k] = __expf(-d);
      }
      *(f32x4*)&orow[t4] = r;
    }
  }
}

// ---------------------------------------------------------------------------
extern "C" void kernel_launch(void* const* d_in, const int* in_sizes, int n_in,
                              void* d_out, int out_size, void* d_ws,
                              size_t ws_size, hipStream_t stream) {
  (void)in_sizes; (void)n_in; (void)out_size; (void)ws_size;
  const float* phi   = (const float*)d_in[0];
  const float* state = (const float*)d_in[1];
  const float* traj  = (const float*)d_in[2];
  const float* A     = (const float*)d_in[3];
  const float* Bin   = (const float*)d_in[4];

  float* out = (float*)d_out;
  float* out_ns = out + (size_t)NB * NM * NT;  // second output: new_state fp32

  char* ws = (char*)d_ws;
  __bf16* ns_bf = (__bf16*)ws;                                  // 2 MB
  __bf16* tj_bf = (__bf16*)(ws + (2u << 20));                   // 1 MB
  float* s_sq   = (float*)(ws + (3u << 20));                    // 32 KB
  float* t_sq   = (float*)(ws + (3u << 20) + (32u << 10));      // 16 KB

  prep_kernel<<<288, 256, 0, stream>>>(phi, state, traj, A, Bin, out_ns, ns_bf,
                                       tj_bf, s_sq, t_sq);
  dim3 g2(NB * NM / 128, NT / 128);  // 64 x 32
  sim_kernel<<<g2, 256, 0, stream>>>(ns_bf, tj_bf, s_sq, t_sq, out);
}